// Round 4
// baseline (85.617 us; speedup 1.0000x reference)
//
#include <hip/hip_runtime.h>

// GeneralizedSurfaceLoss on MI355X.
// Chamfer == Chebyshev distance; BAND_WIDTH=3 => 7x7 neighborhood test.
// R1: killed global-atomic serialization (483 -> 95 us).
// R2: nibble-packed separable window (8 px per uint32, shfl horizontal OR,
//     ds_read_b128 vertical OR), strip blocks, fused finish.
// R4: latency attack. 512-thread blocks (16 waves/CU, was 8); probs loads
//     hoisted to kernel entry so probs+target HBM round-trips overlap;
//     finish kernel batches its group loads before reducing.

#define HH 512
#define WW 512
#define BB 8
#define STRIP 8               // output rows per block; one row per wave
#define SROWS (STRIP + 6)     // staged rows incl. halo = 14
#define NBLK 512              // 64 strips * 8 images

// ws: 9 arrays of NBLK floats; slot s = grp*3+cc (grp: 0=num,1=den,2=mc),
// element index blockFlat = b*64 + strip.

__global__ __launch_bounds__(512) void gsl_stage1(
    const float* __restrict__ probs,   // [B,4,H,W]
    const int*   __restrict__ target,  // [B,H,W]
    float* __restrict__ ws)
{
    __shared__ uint4 hrow[SROWS * 64];   // {h1,h2,h3,center} per (row,lane)
    __shared__ float redf[8][3];
    __shared__ int   redi[8][3];

    const int tid   = threadIdx.x;
    const int lane  = tid & 63;
    const int wave  = tid >> 6;          // 0..7 = output row within strip
    const int strip = blockIdx.x;        // 0..63
    const int b     = blockIdx.y;        // 0..7
    const int y0    = strip * STRIP;
    const int gy    = y0 + wave;         // this wave's output row (always valid)
    const int* __restrict__ tgt_b = target + b * (HH * WW);

    // ---- prefetch probs for this wave's row: 6 independent float4 loads,
    // issued before any target work so both HBM round-trips overlap.
    const float4* pr1 = (const float4*)(probs + (size_t)(((b * 4) + 1) * HH + gy) * WW);
    const float4* pr2 = (const float4*)(probs + (size_t)(((b * 4) + 2) * HH + gy) * WW);
    const float4* pr3 = (const float4*)(probs + (size_t)(((b * 4) + 3) * HH + gy) * WW);
    const float4 f1a = pr1[lane * 2], f1b = pr1[lane * 2 + 1];
    const float4 f2a = pr2[lane * 2], f2b = pr2[lane * 2 + 1];
    const float4 f3a = pr3[lane * 2], f3b = pr3[lane * 2 + 1];

    // ---- stage target rows: wave w packs staged rows w and w+8 (ri < 14).
    #pragma unroll
    for (int i = 0; i < 2; ++i) {
        const int ri = wave + 8 * i;
        if (ri < SROWS) {
            const int gyt = y0 - 3 + ri;
            uint32_t wv = 0u, h1 = 0u, h2 = 0u, h3 = 0u;
            if ((unsigned)gyt < (unsigned)HH) {        // wave-uniform branch
                const int4* trow = (const int4*)(tgt_b + gyt * WW);
                const int4 t0 = trow[lane * 2];
                const int4 t1 = trow[lane * 2 + 1];
                wv = (1u << t0.x)        | (1u << (t0.y + 4))
                   | (1u << (t0.z + 8))  | (1u << (t0.w + 12))
                   | (1u << (t1.x + 16)) | (1u << (t1.y + 20))
                   | (1u << (t1.z + 24)) | (1u << (t1.w + 28));
                uint32_t wl = __shfl_up(wv, 1, 64);   if (lane == 0)  wl = 0u;
                uint32_t wr = __shfl_down(wv, 1, 64); if (lane == 63) wr = 0u;
                h1 = wv | ((wv << 4)  | (wl >> 28)) | ((wv >> 4)  | (wr << 28));
                h2 = h1 | ((wv << 8)  | (wl >> 24)) | ((wv >> 8)  | (wr << 24));
                h3 = h2 | ((wv << 12) | (wl >> 20)) | ((wv >> 12) | (wr << 20));
            }
            hrow[ri * 64 + lane] = make_uint4(h1, h2, h3, wv);
        }
    }
    __syncthreads();

    // ---- vertical OR for this wave's row: 7 x ds_read_b128.
    const int lr = wave + 3;
    const uint4 r0 = hrow[(lr - 3) * 64 + lane];
    const uint4 r1 = hrow[(lr - 2) * 64 + lane];
    const uint4 r2 = hrow[(lr - 1) * 64 + lane];
    const uint4 r3 = hrow[(lr    ) * 64 + lane];
    const uint4 r4 = hrow[(lr + 1) * 64 + lane];
    const uint4 r5 = hrow[(lr + 2) * 64 + lane];
    const uint4 r6 = hrow[(lr + 3) * 64 + lane];
    const uint32_t p1 = r2.x | r3.x | r4.x;
    const uint32_t p2 = r1.y | r2.y | r3.y | r4.y | r5.y;
    const uint32_t p3 = r0.z | r1.z | r2.z | r3.z | r4.z | r5.z | r6.z;
    const uint32_t cw = r3.w;

    const float pv[3][8] = {
        {f1a.x, f1a.y, f1a.z, f1a.w, f1b.x, f1b.y, f1b.z, f1b.w},
        {f2a.x, f2a.y, f2a.z, f2a.w, f2b.x, f2b.y, f2b.z, f2b.w},
        {f3a.x, f3a.y, f3a.z, f3a.w, f3b.x, f3b.y, f3b.z, f3b.w}};

    float num[3] = {0.f, 0.f, 0.f};
    int   den[3] = {0, 0, 0};
    int   mc [3] = {0, 0, 0};

    #pragma unroll
    for (int j = 0; j < 8; ++j) {
        const uint32_t q1 = (p1 >> (4 * j)) & 15u;
        const uint32_t q2 = (p2 >> (4 * j)) & 15u;
        const uint32_t q3 = (p3 >> (4 * j)) & 15u;
        const uint32_t cb = (cw >> (4 * j)) & 15u;
        #pragma unroll
        for (int k = 0; k < 3; ++k) {
            const uint32_t cm = 2u << k;              // 1<<(k+1)
            const bool v = (cb & cm) != 0u;
            const uint32_t sel = v ? (15u & ~cm) : cm;
            const uint32_t a1 = q1 & sel;
            const uint32_t a2 = q2 & sel;
            const uint32_t a3 = q3 & sel;
            const float df  = a1 ? 1.f : (a2 ? 2.f : 3.f);
            const float err = fabsf(pv[k][j] - (v ? 1.f : 0.f));
            num[k] += a3 ? err * df : 0.f;
            den[k] += a3 ? 1 : 0;
            mc [k] += v  ? 1 : 0;
        }
    }

    // ---- block reduction. Per-lane den/mc <= 8; 64-lane sums <= 512 (16-bit
    // safe); cross-wave sums of 8 packed ints <= 4096 per field.
    int pk0 = den[0] | (den[1] << 16);
    int pk1 = den[2] | (mc[0] << 16);
    int pk2 = mc[1]  | (mc[2] << 16);
    #pragma unroll
    for (int off = 32; off; off >>= 1) {
        num[0] += __shfl_down(num[0], off, 64);
        num[1] += __shfl_down(num[1], off, 64);
        num[2] += __shfl_down(num[2], off, 64);
        pk0    += __shfl_down(pk0,    off, 64);
        pk1    += __shfl_down(pk1,    off, 64);
        pk2    += __shfl_down(pk2,    off, 64);
    }
    if (lane == 0) {
        redf[wave][0] = num[0]; redf[wave][1] = num[1]; redf[wave][2] = num[2];
        redi[wave][0] = pk0;    redi[wave][1] = pk1;    redi[wave][2] = pk2;
    }
    __syncthreads();
    if (tid == 0) {
        const int blockFlat = b * 64 + strip;
        float n0 = 0.f, n1 = 0.f, n2 = 0.f;
        int s0 = 0, s1 = 0, s2 = 0;
        #pragma unroll
        for (int w = 0; w < 8; ++w) {
            n0 += redf[w][0]; n1 += redf[w][1]; n2 += redf[w][2];
            s0 += redi[w][0]; s1 += redi[w][1]; s2 += redi[w][2];
        }
        ws[(0 * 3 + 0) * NBLK + blockFlat] = n0;
        ws[(0 * 3 + 1) * NBLK + blockFlat] = n1;
        ws[(0 * 3 + 2) * NBLK + blockFlat] = n2;
        ws[(1 * 3 + 0) * NBLK + blockFlat] = (float)(s0 & 0xFFFF);
        ws[(1 * 3 + 1) * NBLK + blockFlat] = (float)(s0 >> 16);
        ws[(1 * 3 + 2) * NBLK + blockFlat] = (float)(s1 & 0xFFFF);
        ws[(2 * 3 + 0) * NBLK + blockFlat] = (float)(s1 >> 16);
        ws[(2 * 3 + 1) * NBLK + blockFlat] = (float)(s2 & 0xFFFF);
        ws[(2 * 3 + 2) * NBLK + blockFlat] = (float)(s2 >> 16);
    }
}

// Single block, 16 waves. Each wave grabs up to 5 groups; loads for all its
// groups are issued back-to-back (independent) before the shuffle reduces,
// so one HBM latency round instead of five.
__global__ __launch_bounds__(1024) void gsl_finish(
    const float* __restrict__ ws, float* __restrict__ out)
{
    __shared__ float ws2[72];
    const int tid = threadIdx.x, lane = tid & 63, wave = tid >> 6;

    float s[5];
    #pragma unroll
    for (int i = 0; i < 5; ++i) {
        const int g = wave * 5 + i;              // 0..79; 72..79 idle
        if (g < 72) {
            const int grp = g / 24, rem = g - grp * 24;
            const int bb = rem / 3, cc = rem - bb * 3;
            s[i] = ws[(grp * 3 + cc) * NBLK + bb * 64 + lane];
        } else s[i] = 0.f;
    }
    #pragma unroll
    for (int i = 0; i < 5; ++i) {
        #pragma unroll
        for (int off = 32; off; off >>= 1) s[i] += __shfl_down(s[i], off, 64);
    }
    if (lane == 0) {
        #pragma unroll
        for (int i = 0; i < 5; ++i) {
            const int g = wave * 5 + i;
            if (g < 72) ws2[g] = s[i];
        }
    }
    __syncthreads();

    if (wave == 0) {
        float loss = 0.f, incl = 0.f;
        if (lane < 24) {
            const float num = ws2[lane];
            const float den = ws2[24 + lane];
            const float mcv = ws2[48 + lane];
            const bool trivial = (mcv == 0.f) || (mcv == (float)(HH * WW));
            if (trivial) {
                incl = 1.f; loss = 0.f;        // band = whole image, num = 0
            } else if (den >= 32.f) {
                incl = 1.f;
                loss = num / (den + 1e-6f);
            }
        }
        #pragma unroll
        for (int off = 32; off; off >>= 1) {
            loss += __shfl_down(loss, off, 64);
            incl += __shfl_down(incl, off, 64);
        }
        if (lane == 0) out[0] = loss / (incl + 1e-6f);
    }
}

extern "C" void kernel_launch(void* const* d_in, const int* in_sizes, int n_in,
                              void* d_out, int out_size, void* d_ws, size_t ws_size,
                              hipStream_t stream)
{
    const float* probs  = (const float*)d_in[0];
    const int*   target = (const int*)d_in[1];
    float* out = (float*)d_out;
    float* ws  = (float*)d_ws;

    dim3 grid1(64, BB);        // 64 row-strips x 8 images
    gsl_stage1<<<grid1, 512, 0, stream>>>(probs, target, ws);
    gsl_finish<<<1, 1024, 0, stream>>>(ws, out);
}